// Round 8
// baseline (72.365 us; speedup 1.0000x reference)
//
#include <hip/hip_runtime.h>

#define LSTRIDE 40
#define LROWS   18
#define LPLANE  720        // 18 rows * 40 cols
#define MSTRIDE 34

__device__ __forceinline__ float fexp2(float x) { return __builtin_amdgcn_exp2f(x); }
__device__ __forceinline__ float flog2(float x) { return __builtin_amdgcn_logf(x); }

struct Node { float o0, o1, o2, s0, s1, s2; };

// L col k <-> global w = w0 - 4 + k ; row r <-> global h = h0 + r
__device__ __forceinline__ Node nd(const float* L, int r, int k) {
    const int i = r * LSTRIDE + k;
    Node n;
    n.o0 = L[i];              n.o1 = L[i + LPLANE];     n.o2 = L[i + 2 * LPLANE];
    n.s0 = L[i + 3 * LPLANE]; n.s1 = L[i + 4 * LPLANE]; n.s2 = L[i + 5 * LPLANE];
    return n;
}

// core symmetric-pair term: wsm*wr*sum(t^0.8) + wl*wsd*sum(t^2)
__device__ __forceinline__ float pair_core(const Node& I, const Node& J,
                                           float wsm, float wl, float wsd)
{
    float d0 = I.o0 - J.o0, d1 = I.o1 - J.o1, d2 = I.o2 - J.o2;
    float sO = fmaf(d0, d0, fmaf(d1, d1, d2 * d2));
    float t0 = fabsf(I.s0 - J.s0) + 1e-8f;
    float t1 = fabsf(I.s1 - J.s1) + 1e-8f;
    float t2 = fabsf(I.s2 - J.s2) + 1e-8f;
    float ps = fexp2(0.8f * flog2(t0)) + fexp2(0.8f * flog2(t1)) + fexp2(0.8f * flog2(t2));
    float wr = fexp2(-0.72134752044448169f * sO);   // exp(-0.5*sO)
    float sq = fmaf(t0, t0, fmaf(t1, t1, t2 * t2));
    return fmaf(wsm * wr, ps, wl * wsd * sq);
}

// interior pixel: all pair multiplicities are 1
__device__ __forceinline__ float pixel_fast(
    const Node& C, const Node& E, const Node& S, const Node& SE, const Node& SW,
    float mi, float mE, float mS, float mSE, float mSW)
{
    float a = fmaf(mi, 3e-16f - 1.1943215e-6f, 1.1943215e-6f);  // center offset
    a += pair_core(C, E,  2.f - mi - mE,  mi + mE,  0.60653065971263342f);
    a += pair_core(C, S,  2.f - mi - mS,  mi + mS,  0.60653065971263342f);
    a += pair_core(C, SE, 2.f - mi - mSE, mi + mSE, 0.36787944117144233f);
    a += pair_core(C, SW, 2.f - mi - mSW, mi + mSW, 0.36787944117144233f);
    return a;
}

// border pixel: reflection multiplicities / zero weights
__device__ __forceinline__ float pixel_border(
    const Node& C, const Node& E, const Node& S, const Node& SE, const Node& SW,
    float mi, float mE, float mS, float mSE, float mSW, int h, int w)
{
    float aE = (w == 0)   ? 2.f : 1.f, bE = (w == 510) ? 2.f : 1.f;
    float aS = (h == 0)   ? 2.f : 1.f, bS = (h == 510) ? 2.f : 1.f;
    float aW = (w == 511) ? 2.f : 1.f, bW = (w == 1)   ? 2.f : 1.f;
    bool  vE = (w <= 510), vS = (h <= 510);
    bool  vD = vS && vE,   vW = vS && (w >= 1);
    float cEf = vE ? aE : 0.f,      cEb = vE ? bE : 0.f;
    float cSf = vS ? aS : 0.f,      cSb = vS ? bS : 0.f;
    float cDf = vD ? aS * aE : 0.f, cDb = vD ? bS * bE : 0.f;
    float cWf = vW ? aS * aW : 0.f, cWb = vW ? bS * bW : 0.f;

    float a = fmaf(mi, 3e-16f - 1.1943215e-6f, 1.1943215e-6f);
    a += pair_core(C, E,  fmaf(cEf, -mi, cEf) + fmaf(cEb, -mE,  cEb), fmaf(cEf, mi, cEb * mE),  0.60653065971263342f);
    a += pair_core(C, S,  fmaf(cSf, -mi, cSf) + fmaf(cSb, -mS,  cSb), fmaf(cSf, mi, cSb * mS),  0.60653065971263342f);
    a += pair_core(C, SE, fmaf(cDf, -mi, cDf) + fmaf(cDb, -mSE, cDb), fmaf(cDf, mi, cDb * mSE), 0.36787944117144233f);
    a += pair_core(C, SW, fmaf(cWf, -mi, cWf) + fmaf(cWb, -mSW, cWb), fmaf(cWf, mi, cWb * mSW), 0.36787944117144233f);
    return a;
}

__global__ __launch_bounds__(256, 4) void smooth_loss_kernel(
    const float* __restrict__ orig, const float* __restrict__ smo,
    float* __restrict__ out)
{
    __shared__ float L[6 * LPLANE];           // 4320 floats = 17.3 KB
    __shared__ unsigned char Mm[17 * MSTRIDE];// 578 B; (r, cm) <-> (h0+r, w0-1+cm)
    __shared__ float wsum[4];

    const int bid  = blockIdx.x;        // 8 imgs * 32 trow * 16 tcol
    const int b    = bid >> 9;
    const int t    = bid & 511;
    const int trow = t >> 4;
    const int tcol = t & 15;
    const int h0 = trow << 4;           // 16-row tile
    const int w0 = tcol << 5;           // 32-col tile
    const int tid = threadIdx.x;
    const bool border = (tcol == 0) | (tcol == 15) | (trow == 0) | (trow == 31);

    // ---- staging: 1080 float4 jobs (6 planes x 18 rows x 10 chunks) ----
    for (int it = 0; it < 5; ++it) {
        const int j = it * 256 + tid;
        const int p   = j / 180;          // 180 = 18 rows * 10 chunks
        const int rem = j - p * 180;
        const int r   = rem / 10;
        const int q   = rem - r * 10;
        int gh = h0 + r; gh = gh > 511 ? 1022 - gh : gh;
        int wb = w0 - 4 + (q << 2);
        wb = wb < 0 ? 0 : (wb > 508 ? 508 : wb);   // clamped garbage lands only in zero-weight slots
        const float* base = (p < 3) ? orig : smo;
        const int ch = (p < 3) ? p : p - 3;
        const float* gp = base + ((b * 3 + ch) << 18) + (gh << 9) + wb;
        if (j < 1080)
            __builtin_amdgcn_global_load_lds(
                (const __attribute__((address_space(1))) unsigned int*)gp,
                (__attribute__((address_space(3))) unsigned int*)&L[(it * 256 + (tid & ~63)) * 4],
                16, 0, 0);
    }
    __syncthreads();

    // ---- fix-up (tcol==15 only): k=36 <-> w=512 -> reflect 510 (feeds live mask at col 511) ----
    if (tcol == 15) {
        for (int j2 = tid; j2 < 108; j2 += 256) {
            const int p = j2 / 18, r = j2 - p * 18;
            int gh = h0 + r; gh = gh > 511 ? 1022 - gh : gh;
            const float* base = (p < 3) ? orig : smo;
            const int ch = (p < 3) ? p : p - 3;
            L[p * LPLANE + r * LSTRIDE + 36] = base[((b * 3 + ch) << 18) + (gh << 9) + 510];
        }
        __syncthreads();
    }

    // ---- pass 1: mask plane (17 rows x 34 cols), uchar ----
    for (int e = tid; e < 578; e += 256) {
        const int r = e / 34, cm = e - r * 34;
        const int vb = r * LSTRIDE + cm + 3;    // k = cm+3 <-> w = w0-1+cm
        float eo = 0.f, es = 0.f;
        #pragma unroll
        for (int p = 0; p < 3; ++p) {
            float c0 = L[p * LPLANE + vb];
            float d1 = c0 - L[p * LPLANE + vb + LSTRIDE];
            float d2 = c0 - L[p * LPLANE + vb + 1];
            eo += d1 * d1 + d2 * d2;
            float c1 = L[(p + 3) * LPLANE + vb];
            float f1 = c1 - L[(p + 3) * LPLANE + vb + LSTRIDE];
            float f2 = c1 - L[(p + 3) * LPLANE + vb + 1];
            es += f1 * f1 + f2 * f2;
        }
        Mm[e] = (eo < 1.f && (es - eo) > 1.f) ? 1 : 0;
    }
    __syncthreads();

    // ---- pass 2: vertical pixel pair per thread (rows 2vr, 2vr+1; col c) ----
    const int vr = tid >> 5;            // 0..7
    const int c  = tid & 31;            // 0..31  -> stride-1 LDS banks
    const int r0 = vr << 1;
    const int k  = c + 4;               // L col of pixel col c

    float acc = 0.f;
    {
        // phase 1: rows r0, r0+1
        Node C0 = nd(L, r0,     k), E0 = nd(L, r0,     k + 1);
        Node W1 = nd(L, r0 + 1, k - 1), S1 = nd(L, r0 + 1, k), E1 = nd(L, r0 + 1, k + 1);

        const int mb = r0 * MSTRIDE + c + 1;   // mask idx of (row r0, col c)
        float m00 = (float)Mm[mb],     m0E = (float)Mm[mb + 1];
        float m1W = (float)Mm[mb + MSTRIDE - 1];
        float m10 = (float)Mm[mb + MSTRIDE], m1E = (float)Mm[mb + MSTRIDE + 1];

        if (border) {
            acc += pixel_border(C0, E0, S1, E1, W1, m00, m0E, m10, m1E, m1W,
                                h0 + r0, w0 + c);
        } else {
            acc += pixel_fast(C0, E0, S1, E1, W1, m00, m0E, m10, m1E, m1W);
        }

        // phase 2: row r0+2
        Node W2 = nd(L, r0 + 2, k - 1), S2 = nd(L, r0 + 2, k), E2 = nd(L, r0 + 2, k + 1);
        float m2W = (float)Mm[mb + 2 * MSTRIDE - 1];
        float m20 = (float)Mm[mb + 2 * MSTRIDE], m2E = (float)Mm[mb + 2 * MSTRIDE + 1];

        if (border) {
            acc += pixel_border(S1, E1, S2, E2, W2, m10, m1E, m20, m2E, m2W,
                                h0 + r0 + 1, w0 + c);
        } else {
            acc += pixel_fast(S1, E1, S2, E2, W2, m10, m1E, m20, m2E, m2W);
        }
    }

    acc *= (1.0f / 56623104.0f);        // mean over 8*9*3*512*512

    #pragma unroll
    for (int o = 32; o > 0; o >>= 1)
        acc += __shfl_down(acc, o, 64);

    const int lane = tid & 63;
    const int wid  = tid >> 6;
    if (lane == 0) wsum[wid] = acc;
    __syncthreads();
    if (tid == 0)
        atomicAdd(out, wsum[0] + wsum[1] + wsum[2] + wsum[3]);
}

extern "C" void kernel_launch(void* const* d_in, const int* in_sizes, int n_in,
                              void* d_out, int out_size, void* d_ws, size_t ws_size,
                              hipStream_t stream) {
    const float* orig = (const float*)d_in[0];
    const float* smo  = (const float*)d_in[1];
    float* out = (float*)d_out;

    (void)hipMemsetAsync(out, 0, sizeof(float), stream);
    smooth_loss_kernel<<<4096, 256, 0, stream>>>(orig, smo, out);
}

// Round 9
// 50.446 us; speedup vs baseline: 1.4345x; 1.4345x over previous
//
#include <hip/hip_runtime.h>

#define LSTRIDE 72
#define LPLANE  1296       // 18 rows * 72 cols
#define MSTRIDE 66

__device__ __forceinline__ float fexp2(float x) { return __builtin_amdgcn_exp2f(x); }
__device__ __forceinline__ float flog2(float x) { return __builtin_amdgcn_logf(x); }

struct Node { float o0, o1, o2, s0, s1, s2; };

// L col k <-> global w = w0 - 4 + k ; row r <-> global h = h0 + r
__device__ __forceinline__ Node nd(const float* L, int r, int k) {
    const int i = r * LSTRIDE + k;
    Node n;
    n.o0 = L[i];              n.o1 = L[i + LPLANE];     n.o2 = L[i + 2 * LPLANE];
    n.s0 = L[i + 3 * LPLANE]; n.s1 = L[i + 4 * LPLANE]; n.s2 = L[i + 5 * LPLANE];
    return n;
}

// core symmetric-pair term: wsm*wr*sum(t^0.8) + wl*wsd*sum(t^2)
__device__ __forceinline__ float pair_core(const Node& I, const Node& J,
                                           float wsm, float wl, float wsd)
{
    float d0 = I.o0 - J.o0, d1 = I.o1 - J.o1, d2 = I.o2 - J.o2;
    float sO = fmaf(d0, d0, fmaf(d1, d1, d2 * d2));
    float t0 = fabsf(I.s0 - J.s0) + 1e-8f;
    float t1 = fabsf(I.s1 - J.s1) + 1e-8f;
    float t2 = fabsf(I.s2 - J.s2) + 1e-8f;
    float ps = fexp2(0.8f * flog2(t0)) + fexp2(0.8f * flog2(t1)) + fexp2(0.8f * flog2(t2));
    float wr = fexp2(-0.72134752044448169f * sO);   // exp(-0.5*sO)
    float sq = fmaf(t0, t0, fmaf(t1, t1, t2 * t2));
    return fmaf(wsm * wr, ps, wl * wsd * sq);
}

// interior pixel: all pair multiplicities are 1
__device__ __forceinline__ float pixel_fast(
    const Node& C, const Node& E, const Node& S, const Node& SE, const Node& SW,
    float mi, float mE, float mS, float mSE, float mSW)
{
    float a = fmaf(mi, 3e-16f - 1.1943215e-6f, 1.1943215e-6f);  // center offset
    a += pair_core(C, E,  2.f - mi - mE,  mi + mE,  0.60653065971263342f);
    a += pair_core(C, S,  2.f - mi - mS,  mi + mS,  0.60653065971263342f);
    a += pair_core(C, SE, 2.f - mi - mSE, mi + mSE, 0.36787944117144233f);
    a += pair_core(C, SW, 2.f - mi - mSW, mi + mSW, 0.36787944117144233f);
    return a;
}

// border pixel: reflection multiplicities / zero weights
__device__ __forceinline__ float pixel_border(
    const Node& C, const Node& E, const Node& S, const Node& SE, const Node& SW,
    float mi, float mE, float mS, float mSE, float mSW, int h, int w)
{
    float aE = (w == 0)   ? 2.f : 1.f, bE = (w == 510) ? 2.f : 1.f;
    float aS = (h == 0)   ? 2.f : 1.f, bS = (h == 510) ? 2.f : 1.f;
    float aW = (w == 511) ? 2.f : 1.f, bW = (w == 1)   ? 2.f : 1.f;
    bool  vE = (w <= 510), vS = (h <= 510);
    bool  vD = vS && vE,   vW = vS && (w >= 1);
    float cEf = vE ? aE : 0.f,      cEb = vE ? bE : 0.f;
    float cSf = vS ? aS : 0.f,      cSb = vS ? bS : 0.f;
    float cDf = vD ? aS * aE : 0.f, cDb = vD ? bS * bE : 0.f;
    float cWf = vW ? aS * aW : 0.f, cWb = vW ? bS * bW : 0.f;

    float a = fmaf(mi, 3e-16f - 1.1943215e-6f, 1.1943215e-6f);
    a += pair_core(C, E,  fmaf(cEf, -mi, cEf) + fmaf(cEb, -mE,  cEb), fmaf(cEf, mi, cEb * mE),  0.60653065971263342f);
    a += pair_core(C, S,  fmaf(cSf, -mi, cSf) + fmaf(cSb, -mS,  cSb), fmaf(cSf, mi, cSb * mS),  0.60653065971263342f);
    a += pair_core(C, SE, fmaf(cDf, -mi, cDf) + fmaf(cDb, -mSE, cDb), fmaf(cDf, mi, cDb * mSE), 0.36787944117144233f);
    a += pair_core(C, SW, fmaf(cWf, -mi, cWf) + fmaf(cWb, -mSW, cWb), fmaf(cWf, mi, cWb * mSW), 0.36787944117144233f);
    return a;
}

__global__ __launch_bounds__(256, 4) void smooth_loss_kernel(
    const float* __restrict__ orig, const float* __restrict__ smo,
    float* __restrict__ out)
{
    __shared__ float L[6 * LPLANE];           // 7776 floats = 31.1 KB
    __shared__ unsigned char Mm[17 * MSTRIDE];// 1122 B; (r, cm) <-> (h0+r, w0-1+cm)
    __shared__ float wsum[4];

    const int bid  = blockIdx.x;        // 8 imgs * 32 trow * 8 tcol
    const int b    = bid >> 8;
    const int t    = bid & 255;
    const int trow = t >> 3;
    const int tcol = t & 7;
    const int h0 = trow << 4;           // 16-row tile
    const int w0 = tcol << 6;           // 64-col tile
    const int tid = threadIdx.x;
    const bool border = (tcol == 0) | (tcol == 7) | (trow == 0) | (trow == 31);

    // ---- staging: 1944 float4 jobs (6 planes x 18 rows x 18 chunks) ----
    for (int it = 0; it < 8; ++it) {
        const int j = it * 256 + tid;
        const int p   = j / 324;          // 324 = 18 rows * 18 chunks
        const int rem = j - p * 324;
        const int r   = rem / 18;
        const int q   = rem - r * 18;
        int gh = h0 + r; gh = gh > 511 ? 1022 - gh : gh;
        int wb = w0 - 4 + (q << 2);
        wb = wb < 0 ? 0 : (wb > 508 ? 508 : wb);   // clamped garbage lands only in zero-weight slots
        const float* base = (p < 3) ? orig : smo;
        const int ch = (p < 3) ? p : p - 3;
        const float* gp = base + ((b * 3 + ch) << 18) + (gh << 9) + wb;
        if (j < 1944)
            __builtin_amdgcn_global_load_lds(
                (const __attribute__((address_space(1))) unsigned int*)gp,
                (__attribute__((address_space(3))) unsigned int*)&L[(it * 256 + (tid & ~63)) * 4],
                16, 0, 0);
    }
    __syncthreads();

    // ---- fix-up (tcol==7 only): k=68 <-> w=512 -> reflect 510 (feeds the live mask at col 511) ----
    if (tcol == 7) {
        for (int j2 = tid; j2 < 108; j2 += 256) {
            const int p = j2 / 18, r = j2 - p * 18;
            int gh = h0 + r; gh = gh > 511 ? 1022 - gh : gh;
            const float* base = (p < 3) ? orig : smo;
            const int ch = (p < 3) ? p : p - 3;
            L[p * LPLANE + r * LSTRIDE + 68] = base[((b * 3 + ch) << 18) + (gh << 9) + 510];
        }
        __syncthreads();
    }

    // ---- pass 1: mask plane (17 rows x 66 cols), uchar ----
    for (int e = tid; e < 1122; e += 256) {
        const int r = e / 66, cm = e - r * 66;
        const int vb = r * LSTRIDE + cm + 3;    // k = cm+3 <-> w = w0-1+cm
        float eo = 0.f, es = 0.f;
        #pragma unroll
        for (int p = 0; p < 3; ++p) {
            float c0 = L[p * LPLANE + vb];
            float d1 = c0 - L[p * LPLANE + vb + LSTRIDE];
            float d2 = c0 - L[p * LPLANE + vb + 1];
            eo += d1 * d1 + d2 * d2;
            float c1 = L[(p + 3) * LPLANE + vb];
            float f1 = c1 - L[(p + 3) * LPLANE + vb + LSTRIDE];
            float f2 = c1 - L[(p + 3) * LPLANE + vb + 1];
            es += f1 * f1 + f2 * f2;
        }
        Mm[e] = (eo < 1.f && (es - eo) > 1.f) ? 1 : 0;
    }
    __syncthreads();

    // ---- pass 2: 2x2 quad per thread, ALL loads batched before compute ----
    const int qr = tid >> 5;            // 0..7  -> pixel rows 2qr, 2qr+1
    const int qc = tid & 31;            // 0..31 -> pixel cols 2qc, 2qc+1
    const int r0 = qr << 1;
    const int c0 = qc << 1;
    const int kb = c0 + 3;              // k of col c0-1

    // 11 nodes: one independent batch of 66 ds_reads
    Node A1 = nd(L, r0,     kb + 1), A2 = nd(L, r0, kb + 2), A3 = nd(L, r0, kb + 3);
    Node B0 = nd(L, r0 + 1, kb),     B1 = nd(L, r0 + 1, kb + 1);
    Node B2 = nd(L, r0 + 1, kb + 2), B3 = nd(L, r0 + 1, kb + 3);
    Node C0 = nd(L, r0 + 2, kb),     C1 = nd(L, r0 + 2, kb + 1);
    Node C2 = nd(L, r0 + 2, kb + 2), C3 = nd(L, r0 + 2, kb + 3);

    // 11 masks
    const int mb = r0 * MSTRIDE + c0 + 1;     // Mm index of (row r0, col c0)
    float mA1 = (float)Mm[mb],     mA2 = (float)Mm[mb + 1], mA3 = (float)Mm[mb + 2];
    float mB0 = (float)Mm[mb + MSTRIDE - 1], mB1 = (float)Mm[mb + MSTRIDE];
    float mB2 = (float)Mm[mb + MSTRIDE + 1], mB3 = (float)Mm[mb + MSTRIDE + 2];
    float mC0 = (float)Mm[mb + 2 * MSTRIDE - 1], mC1 = (float)Mm[mb + 2 * MSTRIDE];
    float mC2 = (float)Mm[mb + 2 * MSTRIDE + 1], mC3 = (float)Mm[mb + 2 * MSTRIDE + 2];

    float acc = 0.f;
    if (border) {
        acc += pixel_border(A1, A2, B1, B2, B0, mA1, mA2, mB1, mB2, mB0, h0 + r0,     w0 + c0);
        acc += pixel_border(A2, A3, B2, B3, B1, mA2, mA3, mB2, mB3, mB1, h0 + r0,     w0 + c0 + 1);
        acc += pixel_border(B1, B2, C1, C2, C0, mB1, mB2, mC1, mC2, mC0, h0 + r0 + 1, w0 + c0);
        acc += pixel_border(B2, B3, C2, C3, C1, mB2, mB3, mC2, mC3, mC1, h0 + r0 + 1, w0 + c0 + 1);
    } else {
        acc += pixel_fast(A1, A2, B1, B2, B0, mA1, mA2, mB1, mB2, mB0);
        acc += pixel_fast(A2, A3, B2, B3, B1, mA2, mA3, mB2, mB3, mB1);
        acc += pixel_fast(B1, B2, C1, C2, C0, mB1, mB2, mC1, mC2, mC0);
        acc += pixel_fast(B2, B3, C2, C3, C1, mB2, mB3, mC2, mC3, mC1);
    }

    acc *= (1.0f / 56623104.0f);        // mean over 8*9*3*512*512

    #pragma unroll
    for (int o = 32; o > 0; o >>= 1)
        acc += __shfl_down(acc, o, 64);

    const int lane = tid & 63;
    const int wid  = tid >> 6;
    if (lane == 0) wsum[wid] = acc;
    __syncthreads();
    if (tid == 0)
        atomicAdd(out, wsum[0] + wsum[1] + wsum[2] + wsum[3]);
}

extern "C" void kernel_launch(void* const* d_in, const int* in_sizes, int n_in,
                              void* d_out, int out_size, void* d_ws, size_t ws_size,
                              hipStream_t stream) {
    const float* orig = (const float*)d_in[0];
    const float* smo  = (const float*)d_in[1];
    float* out = (float*)d_out;

    (void)hipMemsetAsync(out, 0, sizeof(float), stream);
    smooth_loss_kernel<<<2048, 256, 0, stream>>>(orig, smo, out);
}

// Round 10
// 33.853 us; speedup vs baseline: 2.1376x; 1.4901x over previous
//
#include <hip/hip_runtime.h>

__device__ __forceinline__ float fexp2(float x) { return __builtin_amdgcn_exp2f(x); }
__device__ __forceinline__ float flog2(float x) { return __builtin_amdgcn_logf(x); }

struct Node { float o0, o1, o2, s0, s1, s2; };

// core symmetric-pair term: wsm*wr*sum(t^0.8) + wl*wsd*sum(t^2)
__device__ __forceinline__ float pair_core(const Node& I, const Node& J,
                                           float wsm, float wl, float wsd)
{
    float d0 = I.o0 - J.o0, d1 = I.o1 - J.o1, d2 = I.o2 - J.o2;
    float sO = fmaf(d0, d0, fmaf(d1, d1, d2 * d2));
    float t0 = fabsf(I.s0 - J.s0) + 1e-8f;
    float t1 = fabsf(I.s1 - J.s1) + 1e-8f;
    float t2 = fabsf(I.s2 - J.s2) + 1e-8f;
    float ps = fexp2(0.8f * flog2(t0)) + fexp2(0.8f * flog2(t1)) + fexp2(0.8f * flog2(t2));
    float wr = fexp2(-0.72134752044448169f * sO);   // exp(-0.5*sO)
    float sq = fmaf(t0, t0, fmaf(t1, t1, t2 * t2));
    return fmaf(wsm * wr, ps, wl * wsd * sq);
}

// pixel with reflection multiplicities / zero weights (verified exact R4-R9)
__device__ __forceinline__ float pixel_border(
    const Node& C, const Node& E, const Node& S, const Node& SE, const Node& SW,
    float mi, float mE, float mS, float mSE, float mSW, int h, int w)
{
    float aE = (w == 0)   ? 2.f : 1.f, bE = (w == 510) ? 2.f : 1.f;
    float aS = (h == 0)   ? 2.f : 1.f, bS = (h == 510) ? 2.f : 1.f;
    float aW = (w == 511) ? 2.f : 1.f, bW = (w == 1)   ? 2.f : 1.f;
    bool  vE = (w <= 510), vS = (h <= 510);
    bool  vD = vS && vE,   vW = vS && (w >= 1);
    float cEf = vE ? aE : 0.f,      cEb = vE ? bE : 0.f;
    float cSf = vS ? aS : 0.f,      cSb = vS ? bS : 0.f;
    float cDf = vD ? aS * aE : 0.f, cDb = vD ? bS * bE : 0.f;
    float cWf = vW ? aS * aW : 0.f, cWb = vW ? bS * bW : 0.f;

    float a = fmaf(mi, 3e-16f - 1.1943215e-6f, 1.1943215e-6f);  // center offset
    a += pair_core(C, E,  fmaf(cEf, -mi, cEf) + fmaf(cEb, -mE,  cEb), fmaf(cEf, mi, cEb * mE),  0.60653065971263342f);
    a += pair_core(C, S,  fmaf(cSf, -mi, cSf) + fmaf(cSb, -mS,  cSb), fmaf(cSf, mi, cSb * mS),  0.60653065971263342f);
    a += pair_core(C, SE, fmaf(cDf, -mi, cDf) + fmaf(cDb, -mSE, cDb), fmaf(cDf, mi, cDb * mSE), 0.36787944117144233f);
    a += pair_core(C, SW, fmaf(cWf, -mi, cWf) + fmaf(cWb, -mSW, cWb), fmaf(cWf, mi, cWb * mSW), 0.36787944117144233f);
    return a;
}

// load one image row's 5-col window (c0-1..c0+3, reflected) for all 6 planes
__device__ __forceinline__ void load_row(float R[6][5], const float* const pb[6],
                                         int row, int cm1, int c0, int c2, int c3)
{
    int gh = row > 511 ? 1022 - row : row;
    #pragma unroll
    for (int p = 0; p < 6; ++p) {
        const float* g = pb[p] + (gh << 9);
        R[p][0] = g[cm1];
        float2 v = *(const float2*)(g + c0);
        R[p][1] = v.x; R[p][2] = v.y;
        R[p][3] = g[c2];
        R[p][4] = g[c3];
    }
}

// mask of B_'s row (cols c0-1..c0+2) using C_ = next row
__device__ __forceinline__ void mask_row(float M[4], const float B_[6][5], const float C_[6][5])
{
    #pragma unroll
    for (int j = 0; j < 4; ++j) {
        float eo = 0.f, es = 0.f;
        #pragma unroll
        for (int p = 0; p < 3; ++p) {
            float a = B_[p][j];
            float d1 = a - C_[p][j], d2 = a - B_[p][j + 1];
            eo += d1 * d1 + d2 * d2;
            float s = B_[p + 3][j];
            float f1 = s - C_[p + 3][j], f2 = s - B_[p + 3][j + 1];
            es += f1 * f1 + f2 * f2;
        }
        M[j] = (eo < 1.f && es - eo > 1.f) ? 1.f : 0.f;
    }
}

__device__ __forceinline__ Node mknode(const float R[6][5], int i)
{
    Node n; n.o0 = R[0][i]; n.o1 = R[1][i]; n.o2 = R[2][i];
    n.s0 = R[3][i]; n.s1 = R[4][i]; n.s2 = R[5][i]; return n;
}

// one march step: A=row r, B=row r+1, C=row r+2; N gets row r+3 (issued early)
#define MSTEP(A_, B_, C_, N_, S_, DOLOAD_)                                        \
    {                                                                             \
        if (DOLOAD_) load_row(N_, pb, h0 + (S_) + 3, cm1, c0, c2, c3);            \
        float mN[4]; mask_row(mN, B_, C_);                                        \
        const int hh = h0 + (S_);                                                 \
        acc += pixel_border(mknode(A_,1), mknode(A_,2), mknode(B_,1),             \
                            mknode(B_,2), mknode(B_,0),                           \
                            mC[1], mC[2], mN[1], mN[2], mN[0], hh, c0);           \
        acc += pixel_border(mknode(A_,2), mknode(A_,3), mknode(B_,2),             \
                            mknode(B_,3), mknode(B_,1),                           \
                            mC[2], mC[3], mN[2], mN[3], mN[1], hh, c0 + 1);       \
        mC[0] = mN[0]; mC[1] = mN[1]; mC[2] = mN[2]; mC[3] = mN[3];               \
    }

__global__ __launch_bounds__(256, 2) void smooth_loss_kernel(
    const float* __restrict__ orig, const float* __restrict__ smo,
    float* __restrict__ out)
{
    const int tid  = threadIdx.x;
    const int bid  = blockIdx.x;        // 8 imgs * 64 bands
    const int b    = bid >> 6;
    const int band = bid & 63;
    const int h0   = band << 3;         // 8-row segment
    const int c0   = tid << 1;          // cols c0, c0+1

    // reflected col indices for the 5-col window
    const int cm1 = (c0 == 0) ? 1 : c0 - 1;
    const int c2  = (c0 + 2 > 511) ? 1022 - (c0 + 2) : c0 + 2;
    const int c3  = (c0 + 3 > 511) ? 1022 - (c0 + 3) : c0 + 3;

    const float* pb[6];
    #pragma unroll
    for (int p = 0; p < 3; ++p) {
        pb[p]     = orig + ((b * 3 + p) << 18);
        pb[p + 3] = smo  + ((b * 3 + p) << 18);
    }

    float D0[6][5], D1[6][5], D2[6][5], D3[6][5];
    float mC[4];
    float acc = 0.f;

    load_row(D0, pb, h0,     cm1, c0, c2, c3);
    load_row(D1, pb, h0 + 1, cm1, c0, c2, c3);
    load_row(D2, pb, h0 + 2, cm1, c0, c2, c3);
    mask_row(mC, D0, D1);               // mask row h0

    MSTEP(D0, D1, D2, D3, 0, 1)
    MSTEP(D1, D2, D3, D0, 1, 1)
    MSTEP(D2, D3, D0, D1, 2, 1)
    MSTEP(D3, D0, D1, D2, 3, 1)
    MSTEP(D0, D1, D2, D3, 4, 1)
    MSTEP(D1, D2, D3, D0, 5, 1)
    MSTEP(D2, D3, D0, D1, 6, 1)
    MSTEP(D3, D0, D1, D2, 7, 0)

    acc *= (1.0f / 56623104.0f);        // mean over 8*9*3*512*512

    #pragma unroll
    for (int o = 32; o > 0; o >>= 1)
        acc += __shfl_down(acc, o, 64);

    __shared__ float wsum[4];
    const int lane = tid & 63;
    const int wid  = tid >> 6;
    if (lane == 0) wsum[wid] = acc;
    __syncthreads();
    if (tid == 0)
        atomicAdd(out, wsum[0] + wsum[1] + wsum[2] + wsum[3]);
}

extern "C" void kernel_launch(void* const* d_in, const int* in_sizes, int n_in,
                              void* d_out, int out_size, void* d_ws, size_t ws_size,
                              hipStream_t stream) {
    const float* orig = (const float*)d_in[0];
    const float* smo  = (const float*)d_in[1];
    float* out = (float*)d_out;

    (void)hipMemsetAsync(out, 0, sizeof(float), stream);
    smooth_loss_kernel<<<512, 256, 0, stream>>>(orig, smo, out);
}